// Round 4
// baseline (91.228 us; speedup 1.0000x reference)
//
#include <hip/hip_runtime.h>

// Problem constants (fixed by the reference)
constexpr int B = 8, T = 128, S = 256, H = 512;

typedef __attribute__((ext_vector_type(4))) float f32x4;
typedef __attribute__((ext_vector_type(8))) short short8;
typedef __attribute__((ext_vector_type(4))) short short4v;

#define DEVINL __device__ __forceinline__

DEVINL float bf2f(short s) {
  union { unsigned u; float f; } x;
  x.u = ((unsigned)(unsigned short)s) << 16;
  return x.f;
}
// fp32 -> bf16 round-to-nearest-even (finite inputs)
DEVINL short f2bf(float f) {
  unsigned u = __float_as_uint(f);
  return (short)((u + 0x7fffu + ((u >> 16) & 1u)) >> 16);
}
DEVINL float fast_tanh(float x) {
  float e = __builtin_amdgcn_exp2f(x * 2.8853900817779268f);
  return 1.0f - 2.0f * __builtin_amdgcn_rcpf(e + 1.0f);
}

constexpr float C2 = 2.8853900817779268f;   // 2*log2(e) — folded into W_s, W_h
constexpr float L2E = 1.4426950408889634f;  // log2(e)

// ---- workspace layout (units: shorts) ----
constexpr size_t OFF_WSB = 0;                               // C2*W_s bf16  (H*H)
constexpr size_t OFF_WHB = OFF_WSB + (size_t)H * H;         // C2*W_h bf16  (H*H)
constexpr size_t OFF_WOB = OFF_WHB + (size_t)H * H;         // W_out bf16   (H*2H)
constexpr size_t OFF_HS  = OFF_WOB + (size_t)H * 2 * H;     // hs' bf16     (B*S*H)
constexpr size_t OFF_ET  = OFF_HS + (size_t)B * S * H;      // enc^T bf16   (B*H*S)
constexpr size_t OFF_ATT = OFF_ET + (size_t)B * H * S;      // attn bf16    (B*T*S)
constexpr size_t OFF_CTX = OFF_ATT + (size_t)B * T * S;     // ctx bf16     (B*T*H)
constexpr size_t OFF_QSF = OFF_CTX + (size_t)B * T * H;     // qs' f32      (B*T*H floats = 2x shorts)
// total = 4,980,736 shorts ≈ 9.5 MiB

// ---- weights fp32 -> bf16 (W_s, W_h pre-scaled by C2) ----
// vec4 counts: Ws 65536 | Wh 65536 | Wo 131072 ; cum 65536,131072,262144
__global__ __launch_bounds__(256) void convert_kernel(
    const float* __restrict__ ws, const float* __restrict__ wh,
    const float* __restrict__ wo, short* __restrict__ base) {
  int vi = blockIdx.x * 256 + threadIdx.x;
  if (vi >= 262144) return;
  const float* src; short* dst; int local; float scale;
  if (vi < 65536)       { src = ws; dst = base + OFF_WSB; local = vi;          scale = C2; }
  else if (vi < 131072) { src = wh; dst = base + OFF_WHB; local = vi - 65536;  scale = C2; }
  else                  { src = wo; dst = base + OFF_WOB; local = vi - 131072; scale = 1.f; }
  float4 f = reinterpret_cast<const float4*>(src)[local];
  short4v o;
  o.x = f2bf(f.x * scale); o.y = f2bf(f.y * scale);
  o.z = f2bf(f.z * scale); o.w = f2bf(f.w * scale);
  *reinterpret_cast<short4v*>(dst + (size_t)local * 4) = o;
}

// ---- enc (B,S,H) f32 -> enc^T (B,H,S) bf16, LDS-tiled ----
__global__ __launch_bounds__(256) void transpose_kernel(
    const float* __restrict__ enc, short* __restrict__ e_t) {
  __shared__ float tile[64][65];  // +1 pad: read banks (c+r) mod 32 -> 2-way (free)
  const int tid = threadIdx.x;
  const int bid = blockIdx.x;              // B * (S/64) * (H/64) = 8*4*8 = 256
  const int b = bid >> 5;
  const int s0 = ((bid >> 3) & 3) * 64;
  const int h0 = (bid & 7) * 64;
#pragma unroll
  for (int p = 0; p < 4; ++p) {            // load 64x64 f32, coalesced
    const int idx = p * 256 + tid;
    const int r = idx >> 4, c4 = (idx & 15) * 4;
    float4 f = *reinterpret_cast<const float4*>(&enc[(size_t)(b * S + s0 + r) * H + h0 + c4]);
    tile[r][c4 + 0] = f.x; tile[r][c4 + 1] = f.y; tile[r][c4 + 2] = f.z; tile[r][c4 + 3] = f.w;
  }
  __syncthreads();
#pragma unroll
  for (int p = 0; p < 2; ++p) {            // write transposed, bf16, coalesced
    const int chunk = p * 256 + tid;
    const int rr = chunk >> 3, cc0 = (chunk & 7) * 8;  // rr: h-local, cc0: s-local
    short8 o;
#pragma unroll
    for (int j = 0; j < 8; ++j) o[j] = f2bf(tile[cc0 + j][rr]);
    *reinterpret_cast<short8*>(&e_t[(size_t)(b * H + h0 + rr) * S + s0 + cc0]) = o;
  }
}

// ---- MFMA GEMM core: 64x64 tile, 256 thr (4 waves 2x2), BK=64, XOR-swizzled LDS.
//      C[m][n] = sum_k A[m][k] * Wt[n][k]. A is bf16 or f32 (converted at staging). ----
template <bool AF32>
DEVINL void gemm_tile(const void* __restrict__ Av, int lda,
                      const short* __restrict__ Wt, int ldw, int K,
                      int bm, int bn, short* As, short* Bs, f32x4 acc[2][2]) {
  const int tid = threadIdx.x;
  const int lane = tid & 63;
  const int wm = (tid >> 6) >> 1, wn = (tid >> 6) & 1;
  const int g = lane >> 4, r = lane & 15;
  for (int k0 = 0; k0 < K; k0 += 64) {
    __syncthreads();
#pragma unroll
    for (int p = 0; p < 2; ++p) {
      const int idx = p * 256 + tid;
      const int row = idx >> 3, c = idx & 7;
      short8 av;
      if (AF32) {
        const float* Af = (const float*)Av;
        float4 f1 = *reinterpret_cast<const float4*>(&Af[(size_t)(bm + row) * lda + k0 + c * 8]);
        float4 f2 = *reinterpret_cast<const float4*>(&Af[(size_t)(bm + row) * lda + k0 + c * 8 + 4]);
        av[0] = f2bf(f1.x); av[1] = f2bf(f1.y); av[2] = f2bf(f1.z); av[3] = f2bf(f1.w);
        av[4] = f2bf(f2.x); av[5] = f2bf(f2.y); av[6] = f2bf(f2.z); av[7] = f2bf(f2.w);
      } else {
        const short* Ab = (const short*)Av;
        av = *reinterpret_cast<const short8*>(&Ab[(size_t)(bm + row) * lda + k0 + c * 8]);
      }
      short8 wv = *reinterpret_cast<const short8*>(&Wt[(size_t)(bn + row) * ldw + k0 + c * 8]);
      *reinterpret_cast<short8*>(&As[row * 64 + ((c ^ (row & 7)) * 8)]) = av;
      *reinterpret_cast<short8*>(&Bs[row * 64 + ((c ^ (row & 7)) * 8)]) = wv;
    }
    __syncthreads();
#pragma unroll
    for (int kc = 0; kc < 2; ++kc) {
      short8 af[2], bfr[2];
#pragma unroll
      for (int mb = 0; mb < 2; ++mb) {
        const int ra = wm * 32 + mb * 16 + r;
        af[mb] = *reinterpret_cast<const short8*>(&As[ra * 64 + (((kc * 4 + g) ^ (r & 7)) * 8)]);
      }
#pragma unroll
      for (int nb = 0; nb < 2; ++nb) {
        const int rb = wn * 32 + nb * 16 + r;
        bfr[nb] = *reinterpret_cast<const short8*>(&Bs[rb * 64 + (((kc * 4 + g) ^ (r & 7)) * 8)]);
      }
#pragma unroll
      for (int mb = 0; mb < 2; ++mb)
#pragma unroll
        for (int nb = 0; nb < 2; ++nb)
          acc[mb][nb] = __builtin_amdgcn_mfma_f32_16x16x32_bf16(af[mb], bfr[nb], acc[mb][nb], 0, 0, 0);
    }
  }
}

// qs' = query @ (C2*W_s)^T -> f32 (blocks 0..127); hs' = enc @ (C2*W_h)^T -> bf16 (128..383)
__global__ __launch_bounds__(256) void gemm_proj_kernel(
    const float* __restrict__ query, const float* __restrict__ enc,
    const short* __restrict__ Wsb, const short* __restrict__ Whb,
    float* __restrict__ qs_f, short* __restrict__ hs_bf) {
  __shared__ short As[64 * 64], Bs[64 * 64];
  f32x4 acc[2][2];
#pragma unroll
  for (int i = 0; i < 2; ++i)
#pragma unroll
    for (int j = 0; j < 2; ++j) acc[i][j] = (f32x4){0.f, 0.f, 0.f, 0.f};
  int bid = blockIdx.x;
  const bool is_q = bid < 128;
  const float* A; const short* Wt;
  if (is_q) { A = query; Wt = Wsb; }
  else      { bid -= 128; A = enc; Wt = Whb; }
  const int bm = (bid >> 3) * 64, bn = (bid & 7) * 64;
  gemm_tile<true>(A, H, Wt, H, H, bm, bn, As, Bs, acc);
  const int lane = threadIdx.x & 63, wave = threadIdx.x >> 6;
  const int wm = wave >> 1, wn = wave & 1, g = lane >> 4, r = lane & 15;
#pragma unroll
  for (int mb = 0; mb < 2; ++mb)
#pragma unroll
    for (int nb = 0; nb < 2; ++nb)
#pragma unroll
      for (int i = 0; i < 4; ++i) {
        const int row = bm + wm * 32 + mb * 16 + g * 4 + i;
        const int col = bn + wn * 32 + nb * 16 + r;
        if (is_q) qs_f[(size_t)row * H + col] = acc[mb][nb][i];
        else      hs_bf[(size_t)row * H + col] = f2bf(acc[mb][nb][i]);
      }
}

// ---- scores + softmax -> attn bf16. Block: 512 thr = 8 waves = 4 t-rows x 2 s-halves.
// Wave handles one (t, s-half); lane owns s = sw*128 + {lane, lane+64}.
// q'/v read from global (wave-uniform, L1); hs' bf16 per-lane streams. NO LDS in hot loop.
// score' = -2*L2E * sum_h v_h * rcp(1 + exp2(q'+h'))   [Sum(v) dropped: softmax shift-inv]
__global__ __launch_bounds__(512) void attn_kernel(
    const float* __restrict__ qs_f, const short* __restrict__ hs_bf,
    const float* __restrict__ v, const int* __restrict__ lens,
    short* __restrict__ attn_bf) {
  __shared__ float smax[4][2], ssum[4][2];
  const int tid = threadIdx.x;
  const int lane = tid & 63, wave = tid >> 6;
  const int tl = wave >> 1, sw = wave & 1;
  const int b = blockIdx.x >> 5;           // 32 blocks per batch (T/4)
  const int t = (blockIdx.x & 31) * 4 + tl;
  const int s0 = sw * 128 + lane;          // and s1 = s0 + 64

  const float* qp = qs_f + (size_t)(b * T + t) * H;
  const short* h0p = hs_bf + ((size_t)(b * S) + s0) * H;
  const short* h1p = h0p + (size_t)64 * H;

  float acc0 = 0.f, acc1 = 0.f;
  for (int ch = 0; ch < H / 8; ++ch) {
    const short8 ha = *reinterpret_cast<const short8*>(h0p + ch * 8);
    const short8 hb = *reinterpret_cast<const short8*>(h1p + ch * 8);
    const f32x4 qa = *reinterpret_cast<const f32x4*>(qp + ch * 8);
    const f32x4 qb = *reinterpret_cast<const f32x4*>(qp + ch * 8 + 4);
    const f32x4 va = *reinterpret_cast<const f32x4*>(v + ch * 8);
    const f32x4 vb = *reinterpret_cast<const f32x4*>(v + ch * 8 + 4);
#pragma unroll
    for (int j = 0; j < 4; ++j) {
      float x0 = qa[j] + bf2f(ha[j]);
      float x1 = qa[j] + bf2f(hb[j]);
      float r0 = __builtin_amdgcn_rcpf(__builtin_amdgcn_exp2f(x0) + 1.0f);
      float r1 = __builtin_amdgcn_rcpf(__builtin_amdgcn_exp2f(x1) + 1.0f);
      acc0 = fmaf(va[j], r0, acc0);
      acc1 = fmaf(va[j], r1, acc1);
    }
#pragma unroll
    for (int j = 0; j < 4; ++j) {
      float x0 = qb[j] + bf2f(ha[j + 4]);
      float x1 = qb[j] + bf2f(hb[j + 4]);
      float r0 = __builtin_amdgcn_rcpf(__builtin_amdgcn_exp2f(x0) + 1.0f);
      float r1 = __builtin_amdgcn_rcpf(__builtin_amdgcn_exp2f(x1) + 1.0f);
      acc0 = fmaf(vb[j], r0, acc0);
      acc1 = fmaf(vb[j], r1, acc1);
    }
  }

  const int len = lens[b];
  float y0 = (s0 < len) ? (-2.0f * L2E * acc0) : -1e30f;       // log2-domain scores
  float y1 = (s0 + 64 < len) ? (-2.0f * L2E * acc1) : -1e30f;

  float m = fmaxf(y0, y1);
#pragma unroll
  for (int off = 32; off > 0; off >>= 1) m = fmaxf(m, __shfl_xor(m, off));
  if (lane == 0) smax[tl][sw] = m;
  __syncthreads();
  const float mt = fmaxf(smax[tl][0], smax[tl][1]);
  float p0 = __builtin_amdgcn_exp2f(y0 - mt);
  float p1 = __builtin_amdgcn_exp2f(y1 - mt);
  float sum = p0 + p1;
#pragma unroll
  for (int off = 32; off > 0; off >>= 1) sum += __shfl_xor(sum, off);
  if (lane == 0) ssum[tl][sw] = sum;
  __syncthreads();
  const float rs = __builtin_amdgcn_rcpf(ssum[tl][0] + ssum[tl][1]);

  short* arow = attn_bf + (size_t)(b * T + t) * S;
  arow[s0] = f2bf(p0 * rs);
  arow[s0 + 64] = f2bf(p1 * rs);
}

// ctx = attn @ enc  (via enc^T as Wt). A rows: [B*T][S]; Wt rows: e_t[b][h][s].
__global__ __launch_bounds__(256) void ctx_gemm_kernel(
    const short* __restrict__ attn_bf, const short* __restrict__ e_t,
    short* __restrict__ ctx_bf) {
  __shared__ short As[64 * 64], Bs[64 * 64];
  f32x4 acc[2][2];
#pragma unroll
  for (int i = 0; i < 2; ++i)
#pragma unroll
    for (int j = 0; j < 2; ++j) acc[i][j] = (f32x4){0.f, 0.f, 0.f, 0.f};
  const int bm = blockIdx.x * 64;          // over B*T = 1024 rows
  const int bn = blockIdx.y * 64;          // over H
  const int batch = bm >> 7;               // T = 128 rows per batch
  gemm_tile<false>(attn_bf, S, e_t + (size_t)batch * H * S, S, S, bm, bn, As, Bs, acc);
  const int lane = threadIdx.x & 63, wave = threadIdx.x >> 6;
  const int wm = wave >> 1, wn = wave & 1, g = lane >> 4, r = lane & 15;
#pragma unroll
  for (int mb = 0; mb < 2; ++mb)
#pragma unroll
    for (int nb = 0; nb < 2; ++nb)
#pragma unroll
      for (int i = 0; i < 4; ++i) {
        const int row = bm + wm * 32 + mb * 16 + g * 4 + i;
        const int col = bn + wn * 32 + nb * 16 + r;
        ctx_bf[(size_t)row * H + col] = f2bf(acc[mb][nb][i]);
      }
}

// out = tanh([ctx | query] @ W_out^T + b_out), f32 out.
__global__ __launch_bounds__(256) void gemm_out_kernel(
    const short* __restrict__ ctx_bf, const float* __restrict__ query,
    const short* __restrict__ Wob, const float* __restrict__ bias,
    float* __restrict__ out) {
  __shared__ short As[64 * 64], Bs[64 * 64];
  f32x4 acc[2][2];
#pragma unroll
  for (int i = 0; i < 2; ++i)
#pragma unroll
    for (int j = 0; j < 2; ++j) acc[i][j] = (f32x4){0.f, 0.f, 0.f, 0.f};
  const int bm = (blockIdx.x >> 3) * 64, bn = (blockIdx.x & 7) * 64;
  gemm_tile<false>(ctx_bf, H, Wob, 2 * H, H, bm, bn, As, Bs, acc);
  gemm_tile<true>(query, H, Wob + H, 2 * H, H, bm, bn, As, Bs, acc);
  const int lane = threadIdx.x & 63, wave = threadIdx.x >> 6;
  const int wm = wave >> 1, wn = wave & 1, g = lane >> 4, r = lane & 15;
#pragma unroll
  for (int mb = 0; mb < 2; ++mb)
#pragma unroll
    for (int nb = 0; nb < 2; ++nb) {
      const int col = bn + wn * 32 + nb * 16 + r;
      const float bb = bias[col];
#pragma unroll
      for (int i = 0; i < 4; ++i) {
        const int row = bm + wm * 32 + mb * 16 + g * 4 + i;
        out[(size_t)row * H + col] = fast_tanh(acc[mb][nb][i] + bb);
      }
    }
}

extern "C" void kernel_launch(void* const* d_in, const int* in_sizes, int n_in,
                              void* d_out, int out_size, void* d_ws, size_t ws_size,
                              hipStream_t stream) {
  const float* query = (const float*)d_in[0];  // (B,T,H)
  const float* enc = (const float*)d_in[1];    // (B,S,H)
  const int* lens = (const int*)d_in[2];       // (B)
  const float* W_s = (const float*)d_in[3];    // (H,H)
  const float* W_h = (const float*)d_in[4];    // (H,H)
  const float* v = (const float*)d_in[5];      // (H)
  const float* W_out = (const float*)d_in[6];  // (H,2H)
  const float* b_out = (const float*)d_in[7];  // (H)
  float* out = (float*)d_out;                  // (B,T,H)

  short* wsb = (short*)d_ws;
  short* Wsb = wsb + OFF_WSB;
  short* Whb = wsb + OFF_WHB;
  short* Wob = wsb + OFF_WOB;
  short* hs_bf = wsb + OFF_HS;
  short* e_t = wsb + OFF_ET;
  short* attn_bf = wsb + OFF_ATT;
  short* ctx_bf = wsb + OFF_CTX;
  float* qs_f = (float*)(wsb + OFF_QSF);

  convert_kernel<<<1024, 256, 0, stream>>>(W_s, W_h, W_out, wsb);
  transpose_kernel<<<256, 256, 0, stream>>>(enc, e_t);
  gemm_proj_kernel<<<384, 256, 0, stream>>>(query, enc, Wsb, Whb, qs_f, hs_bf);
  attn_kernel<<<B * T / 4, 512, 0, stream>>>(qs_f, hs_bf, v, lens, attn_bf);
  ctx_gemm_kernel<<<dim3(16, 8), 256, 0, stream>>>(attn_bf, e_t, ctx_bf);
  gemm_out_kernel<<<128, 256, 0, stream>>>(ctx_bf, query, Wob, b_out, out);
}

// Round 5
// 77.433 us; speedup vs baseline: 1.1782x; 1.1782x over previous
//
#include <hip/hip_runtime.h>

// Problem constants (fixed by the reference)
constexpr int B = 8, T = 128, S = 256, H = 512;

typedef __attribute__((ext_vector_type(4))) float f32x4;
typedef __attribute__((ext_vector_type(8))) short short8;
typedef __attribute__((ext_vector_type(4))) short short4v;

#define DEVINL __device__ __forceinline__

DEVINL float bf2f(short s) {
  union { unsigned u; float f; } x;
  x.u = ((unsigned)(unsigned short)s) << 16;
  return x.f;
}
// fp32 -> bf16 round-to-nearest-even (finite inputs)
DEVINL short f2bf(float f) {
  unsigned u = __float_as_uint(f);
  return (short)((u + 0x7fffu + ((u >> 16) & 1u)) >> 16);
}
DEVINL float fast_tanh(float x) {
  float e = __builtin_amdgcn_exp2f(x * 2.8853900817779268f);
  return 1.0f - 2.0f * __builtin_amdgcn_rcpf(e + 1.0f);
}

constexpr float C2 = 2.8853900817779268f;   // 2*log2(e) — folded into W_s, W_h
constexpr float L2E = 1.4426950408889634f;  // log2(e)

// ---- workspace layout (units: shorts) ----
constexpr size_t OFF_WSB = 0;                               // C2*W_s bf16  (H*H)
constexpr size_t OFF_WHB = OFF_WSB + (size_t)H * H;         // C2*W_h bf16  (H*H)
constexpr size_t OFF_WOB = OFF_WHB + (size_t)H * H;         // W_out bf16   (H*2H)
constexpr size_t OFF_HST = OFF_WOB + (size_t)H * 2 * H;     // hs'^T bf16   (B*H*S)
constexpr size_t OFF_ET  = OFF_HST + (size_t)B * H * S;     // enc^T bf16   (B*H*S)
constexpr size_t OFF_ATT = OFF_ET + (size_t)B * H * S;      // attn bf16    (B*T*S)
constexpr size_t OFF_CTX = OFF_ATT + (size_t)B * T * S;     // ctx bf16     (B*T*H)
constexpr size_t OFF_QSF = OFF_CTX + (size_t)B * T * H;     // qs' f32      (B*T*H floats)
// total 4,980,736 shorts ≈ 9.5 MiB

// ---- prep: blocks [0,256): enc f32 -> e_t[b][h][s] bf16 (LDS-tiled transpose);
//            blocks [256,1280): weights fp32 -> bf16 (W_s, W_h pre-scaled by C2) ----
__global__ __launch_bounds__(256) void prep_kernel(
    const float* __restrict__ ws, const float* __restrict__ wh,
    const float* __restrict__ wo, const float* __restrict__ enc,
    short* __restrict__ base) {
  __shared__ float tile[64][65];
  const int tid = threadIdx.x;
  if (blockIdx.x < 256) {
    short* e_t = base + OFF_ET;
    const int bid = blockIdx.x;
    const int b = bid >> 5;
    const int s0 = ((bid >> 3) & 3) * 64;
    const int h0 = (bid & 7) * 64;
#pragma unroll
    for (int p = 0; p < 4; ++p) {
      const int idx = p * 256 + tid;
      const int r = idx >> 4, c4 = (idx & 15) * 4;
      float4 f = *reinterpret_cast<const float4*>(&enc[(size_t)(b * S + s0 + r) * H + h0 + c4]);
      tile[r][c4 + 0] = f.x; tile[r][c4 + 1] = f.y; tile[r][c4 + 2] = f.z; tile[r][c4 + 3] = f.w;
    }
    __syncthreads();
#pragma unroll
    for (int p = 0; p < 2; ++p) {
      const int chunk = p * 256 + tid;
      const int rr = chunk >> 3, cc0 = (chunk & 7) * 8;
      short8 o;
#pragma unroll
      for (int j = 0; j < 8; ++j) o[j] = f2bf(tile[cc0 + j][rr]);
      *reinterpret_cast<short8*>(&e_t[(size_t)(b * H + h0 + rr) * S + s0 + cc0]) = o;
    }
  } else {
    int vi = (blockIdx.x - 256) * 256 + tid;  // vec4 index; Ws 65536 | Wh 65536 | Wo 131072
    if (vi >= 262144) return;
    const float* src; short* dst; int local; float scale;
    if (vi < 65536)       { src = ws; dst = base + OFF_WSB; local = vi;          scale = C2; }
    else if (vi < 131072) { src = wh; dst = base + OFF_WHB; local = vi - 65536;  scale = C2; }
    else                  { src = wo; dst = base + OFF_WOB; local = vi - 131072; scale = 1.f; }
    float4 f = reinterpret_cast<const float4*>(src)[local];
    short4v o;
    o.x = f2bf(f.x * scale); o.y = f2bf(f.y * scale);
    o.z = f2bf(f.z * scale); o.w = f2bf(f.w * scale);
    *reinterpret_cast<short4v*>(dst + (size_t)local * 4) = o;
  }
}

// ---- MFMA GEMM core: 64x64 tile, 256 thr (4 waves 2x2), BK=64, XOR-swizzled LDS.
//      C[m][n] = sum_k A[m][k] * Wt[n][k]. A is bf16 or f32 (converted at staging). ----
template <bool AF32>
DEVINL void gemm_tile(const void* __restrict__ Av, int lda,
                      const short* __restrict__ Wt, int ldw, int K,
                      int bm, int bn, short* As, short* Bs, f32x4 acc[2][2]) {
  const int tid = threadIdx.x;
  const int lane = tid & 63;
  const int wm = (tid >> 6) >> 1, wn = (tid >> 6) & 1;
  const int g = lane >> 4, r = lane & 15;
  for (int k0 = 0; k0 < K; k0 += 64) {
    __syncthreads();
#pragma unroll
    for (int p = 0; p < 2; ++p) {
      const int idx = p * 256 + tid;
      const int row = idx >> 3, c = idx & 7;
      short8 av;
      if (AF32) {
        const float* Af = (const float*)Av;
        float4 f1 = *reinterpret_cast<const float4*>(&Af[(size_t)(bm + row) * lda + k0 + c * 8]);
        float4 f2 = *reinterpret_cast<const float4*>(&Af[(size_t)(bm + row) * lda + k0 + c * 8 + 4]);
        av[0] = f2bf(f1.x); av[1] = f2bf(f1.y); av[2] = f2bf(f1.z); av[3] = f2bf(f1.w);
        av[4] = f2bf(f2.x); av[5] = f2bf(f2.y); av[6] = f2bf(f2.z); av[7] = f2bf(f2.w);
      } else {
        const short* Ab = (const short*)Av;
        av = *reinterpret_cast<const short8*>(&Ab[(size_t)(bm + row) * lda + k0 + c * 8]);
      }
      short8 wv = *reinterpret_cast<const short8*>(&Wt[(size_t)(bn + row) * ldw + k0 + c * 8]);
      *reinterpret_cast<short8*>(&As[row * 64 + ((c ^ (row & 7)) * 8)]) = av;
      *reinterpret_cast<short8*>(&Bs[row * 64 + ((c ^ (row & 7)) * 8)]) = wv;
    }
    __syncthreads();
#pragma unroll
    for (int kc = 0; kc < 2; ++kc) {
      short8 af[2], bfr[2];
#pragma unroll
      for (int mb = 0; mb < 2; ++mb) {
        const int ra = wm * 32 + mb * 16 + r;
        af[mb] = *reinterpret_cast<const short8*>(&As[ra * 64 + (((kc * 4 + g) ^ (r & 7)) * 8)]);
      }
#pragma unroll
      for (int nb = 0; nb < 2; ++nb) {
        const int rb = wn * 32 + nb * 16 + r;
        bfr[nb] = *reinterpret_cast<const short8*>(&Bs[rb * 64 + (((kc * 4 + g) ^ (r & 7)) * 8)]);
      }
#pragma unroll
      for (int mb = 0; mb < 2; ++mb)
#pragma unroll
        for (int nb = 0; nb < 2; ++nb)
          acc[mb][nb] = __builtin_amdgcn_mfma_f32_16x16x32_bf16(af[mb], bfr[nb], acc[mb][nb], 0, 0, 0);
    }
  }
}

// qs' = query @ (C2*W_s)^T -> f32 row-major (blocks 0..127)
// hs' = enc @ (C2*W_h)^T   -> bf16 TRANSPOSED hs_t[b][h][s] (blocks 128..383)
__global__ __launch_bounds__(256) void gemm_proj_kernel(
    const float* __restrict__ query, const float* __restrict__ enc,
    const short* __restrict__ Wsb, const short* __restrict__ Whb,
    float* __restrict__ qs_f, short* __restrict__ hs_t) {
  __shared__ short As[64 * 64], Bs[64 * 64];
  f32x4 acc[2][2];
#pragma unroll
  for (int i = 0; i < 2; ++i)
#pragma unroll
    for (int j = 0; j < 2; ++j) acc[i][j] = (f32x4){0.f, 0.f, 0.f, 0.f};
  int bid = blockIdx.x;
  const bool is_q = bid < 128;
  const float* A; const short* Wt;
  if (is_q) { A = query; Wt = Wsb; }
  else      { bid -= 128; A = enc; Wt = Whb; }
  const int bm = (bid >> 3) * 64, bn = (bid & 7) * 64;
  gemm_tile<true>(A, H, Wt, H, H, bm, bn, As, Bs, acc);
  const int lane = threadIdx.x & 63, wave = threadIdx.x >> 6;
  const int wm = wave >> 1, wn = wave & 1, g = lane >> 4, r = lane & 15;
#pragma unroll
  for (int mb = 0; mb < 2; ++mb)
#pragma unroll
    for (int nb = 0; nb < 2; ++nb) {
      const int m0 = bm + wm * 32 + mb * 16 + g * 4;  // base of 4 consecutive rows
      const int col = bn + wn * 32 + nb * 16 + r;
      if (is_q) {
#pragma unroll
        for (int i = 0; i < 4; ++i) qs_f[(size_t)(m0 + i) * H + col] = acc[mb][nb][i];
      } else {
        // rows are s-consecutive within one b (S=256 divides tiles)
        const int bb = m0 >> 8, sl = m0 & 255;
        short4v o;
        o.x = f2bf(acc[mb][nb][0]); o.y = f2bf(acc[mb][nb][1]);
        o.z = f2bf(acc[mb][nb][2]); o.w = f2bf(acc[mb][nb][3]);
        *reinterpret_cast<short4v*>(&hs_t[((size_t)bb * H + col) * S + sl]) = o;
      }
    }
}

// ---- scores + softmax -> attn bf16.
// Block: 512 thr = 8 waves = 2 t-rows x 4 s-groups; lane owns s = sg*64+lane (1 s/lane).
// hs_t reads coalesced (2B/lane, imm-offset); q'/v wave-uniform (L1 broadcast).
// score' = -2*L2E * sum_h v_h * rcp(1 + exp2(q'+h'))  [Sum(v) dropped: softmax shift-inv]
__global__ __launch_bounds__(512) void attn_kernel(
    const float* __restrict__ qs_f, const short* __restrict__ hs_t,
    const float* __restrict__ v, const int* __restrict__ lens,
    short* __restrict__ attn_bf) {
  __shared__ float red_m[2][4], red_s[2][4];
  const int tid = threadIdx.x, lane = tid & 63, wave = tid >> 6;
  const int tl = wave >> 2, sg = wave & 3;
  const int b = blockIdx.x >> 6;           // 64 blocks per batch (T/2)
  const int t = (blockIdx.x & 63) * 2 + tl;
  const int s = sg * 64 + lane;

  const float* qp = qs_f + (size_t)(b * T + t) * H;
  const short* hp = hs_t + (size_t)b * H * S + s;

  float a0 = 0.f, a1 = 0.f;
  for (int ch = 0; ch < H / 8; ++ch) {
    const int h = ch * 8;
    const f32x4 qa = *reinterpret_cast<const f32x4*>(qp + h);
    const f32x4 qb = *reinterpret_cast<const f32x4*>(qp + h + 4);
    const f32x4 va = *reinterpret_cast<const f32x4*>(v + h);
    const f32x4 vb = *reinterpret_cast<const f32x4*>(v + h + 4);
    const short* hh = hp + (size_t)h * S;
#pragma unroll
    for (int j = 0; j < 4; ++j) {
      float x0 = qa[j] + bf2f(hh[(size_t)j * S]);
      float x1 = qb[j] + bf2f(hh[(size_t)(j + 4) * S]);
      a0 = fmaf(va[j], __builtin_amdgcn_rcpf(__builtin_amdgcn_exp2f(x0) + 1.0f), a0);
      a1 = fmaf(vb[j], __builtin_amdgcn_rcpf(__builtin_amdgcn_exp2f(x1) + 1.0f), a1);
    }
  }
  const float acc = a0 + a1;

  const int len = lens[b];
  const float y = (s < len) ? (-2.0f * L2E * acc) : -1e30f;  // log2-domain score

  float m = y;
#pragma unroll
  for (int off = 32; off > 0; off >>= 1) m = fmaxf(m, __shfl_xor(m, off));
  if (lane == 0) red_m[tl][sg] = m;
  __syncthreads();
  const float mt = fmaxf(fmaxf(red_m[tl][0], red_m[tl][1]),
                         fmaxf(red_m[tl][2], red_m[tl][3]));
  const float p = __builtin_amdgcn_exp2f(y - mt);
  float sum = p;
#pragma unroll
  for (int off = 32; off > 0; off >>= 1) sum += __shfl_xor(sum, off);
  if (lane == 0) red_s[tl][sg] = sum;
  __syncthreads();
  const float tot = red_s[tl][0] + red_s[tl][1] + red_s[tl][2] + red_s[tl][3];
  attn_bf[(size_t)(b * T + t) * S + s] = f2bf(p * __builtin_amdgcn_rcpf(tot));
}

// ctx = attn @ enc  (via e_t as Wt). A rows: [B*T][S]; Wt rows: e_t[b][h][s].
__global__ __launch_bounds__(256) void ctx_gemm_kernel(
    const short* __restrict__ attn_bf, const short* __restrict__ e_t,
    short* __restrict__ ctx_bf) {
  __shared__ short As[64 * 64], Bs[64 * 64];
  f32x4 acc[2][2];
#pragma unroll
  for (int i = 0; i < 2; ++i)
#pragma unroll
    for (int j = 0; j < 2; ++j) acc[i][j] = (f32x4){0.f, 0.f, 0.f, 0.f};
  const int bm = blockIdx.x * 64;          // over B*T = 1024 rows
  const int bn = blockIdx.y * 64;          // over H
  const int batch = bm >> 7;               // T = 128 rows per batch
  gemm_tile<false>(attn_bf, S, e_t + (size_t)batch * H * S, S, S, bm, bn, As, Bs, acc);
  const int lane = threadIdx.x & 63, wave = threadIdx.x >> 6;
  const int wm = wave >> 1, wn = wave & 1, g = lane >> 4, r = lane & 15;
#pragma unroll
  for (int mb = 0; mb < 2; ++mb)
#pragma unroll
    for (int nb = 0; nb < 2; ++nb)
#pragma unroll
      for (int i = 0; i < 4; ++i) {
        const int row = bm + wm * 32 + mb * 16 + g * 4 + i;
        const int col = bn + wn * 32 + nb * 16 + r;
        ctx_bf[(size_t)row * H + col] = f2bf(acc[mb][nb][i]);
      }
}

// out = tanh([ctx | query] @ W_out^T + b_out), f32 out.
__global__ __launch_bounds__(256) void gemm_out_kernel(
    const short* __restrict__ ctx_bf, const float* __restrict__ query,
    const short* __restrict__ Wob, const float* __restrict__ bias,
    float* __restrict__ out) {
  __shared__ short As[64 * 64], Bs[64 * 64];
  f32x4 acc[2][2];
#pragma unroll
  for (int i = 0; i < 2; ++i)
#pragma unroll
    for (int j = 0; j < 2; ++j) acc[i][j] = (f32x4){0.f, 0.f, 0.f, 0.f};
  const int bm = (blockIdx.x >> 3) * 64, bn = (blockIdx.x & 7) * 64;
  gemm_tile<false>(ctx_bf, H, Wob, 2 * H, H, bm, bn, As, Bs, acc);
  gemm_tile<true>(query, H, Wob + H, 2 * H, H, bm, bn, As, Bs, acc);
  const int lane = threadIdx.x & 63, wave = threadIdx.x >> 6;
  const int wm = wave >> 1, wn = wave & 1, g = lane >> 4, r = lane & 15;
#pragma unroll
  for (int mb = 0; mb < 2; ++mb)
#pragma unroll
    for (int nb = 0; nb < 2; ++nb) {
      const int col = bn + wn * 32 + nb * 16 + r;
      const float bb = bias[col];
#pragma unroll
      for (int i = 0; i < 4; ++i) {
        const int row = bm + wm * 32 + mb * 16 + g * 4 + i;
        out[(size_t)row * H + col] = fast_tanh(acc[mb][nb][i] + bb);
      }
    }
}

extern "C" void kernel_launch(void* const* d_in, const int* in_sizes, int n_in,
                              void* d_out, int out_size, void* d_ws, size_t ws_size,
                              hipStream_t stream) {
  const float* query = (const float*)d_in[0];  // (B,T,H)
  const float* enc = (const float*)d_in[1];    // (B,S,H)
  const int* lens = (const int*)d_in[2];       // (B)
  const float* W_s = (const float*)d_in[3];    // (H,H)
  const float* W_h = (const float*)d_in[4];    // (H,H)
  const float* v = (const float*)d_in[5];      // (H)
  const float* W_out = (const float*)d_in[6];  // (H,2H)
  const float* b_out = (const float*)d_in[7];  // (H)
  float* out = (float*)d_out;                  // (B,T,H)

  short* wsb = (short*)d_ws;
  short* Wsb = wsb + OFF_WSB;
  short* Whb = wsb + OFF_WHB;
  short* Wob = wsb + OFF_WOB;
  short* hs_t = wsb + OFF_HST;
  short* e_t = wsb + OFF_ET;
  short* attn_bf = wsb + OFF_ATT;
  short* ctx_bf = wsb + OFF_CTX;
  float* qs_f = (float*)(wsb + OFF_QSF);

  prep_kernel<<<1280, 256, 0, stream>>>(W_s, W_h, W_out, enc, wsb);
  gemm_proj_kernel<<<384, 256, 0, stream>>>(query, enc, Wsb, Whb, qs_f, hs_t);
  attn_kernel<<<512, 512, 0, stream>>>(qs_f, hs_t, v, lens, attn_bf);
  ctx_gemm_kernel<<<dim3(16, 8), 256, 0, stream>>>(attn_bf, e_t, ctx_bf);
  gemm_out_kernel<<<128, 256, 0, stream>>>(ctx_bf, query, Wob, b_out, out);
}